// Round 1
// baseline (68227.716 us; speedup 1.0000x reference)
//
#include <hip/hip_runtime.h>
#include <hip/hip_bf16.h>

#define TT 512
#define BB 64
#define DD 1024
#define HH 1024
#define NG4 4096

typedef short bf16x8 __attribute__((ext_vector_type(8)));
typedef float f32x4 __attribute__((ext_vector_type(4)));
typedef __hip_bfloat16 bf16;

// ---------------- cast: fp32 -> bf16 hi + bf16 lo(residual) ----------------
__global__ __launch_bounds__(256) void cast_hilo(const float* __restrict__ in,
                                                 bf16* __restrict__ hi,
                                                 bf16* __restrict__ lo,
                                                 int n4) {
  int i = blockIdx.x * 256 + threadIdx.x;
  if (i >= n4) return;
  float4 v = reinterpret_cast<const float4*>(in)[i];
  float f[4] = {v.x, v.y, v.z, v.w};
  int base = i * 4;
#pragma unroll
  for (int j = 0; j < 4; ++j) {
    bf16 h = __float2bfloat16(f[j]);
    hi[base + j] = h;
    lo[base + j] = __float2bfloat16(f[j] - __bfloat162float(h));
  }
}

// ---------------- 3-term split-bf16 MFMA GEMM: C = A*B^T + bias1 + bias2 ----
// A: [M][K] (hi/lo bf16), B: [N][K] (hi/lo bf16), C: [M][N] fp32
// 128x128 tile, BK=64, 4 waves, mfma_f32_16x16x32_bf16
#define BM 128
#define BN 128
#define BKK 64

__global__ __launch_bounds__(256) void gemm3(
    const bf16* __restrict__ Ah, const bf16* __restrict__ Al,
    const bf16* __restrict__ Bh, const bf16* __restrict__ Bl,
    const float* __restrict__ bias1, const float* __restrict__ bias2,
    float* __restrict__ C, int M, int N, int K)
{
  __shared__ bf16 sAh[BM][BKK], sAl[BM][BKK], sBh[BN][BKK], sBl[BN][BKK];
  const int tid  = threadIdx.x;
  const int lane = tid & 63;
  const int wv   = tid >> 6;
  const int wr   = wv >> 1, wc = wv & 1;
  const int nbx  = N / BN;
  const int bx   = blockIdx.x % nbx, by = blockIdx.x / nbx;
  const int l15  = lane & 15, l4 = lane >> 4;

  f32x4 acc[4][4] = {};

  for (int k0 = 0; k0 < K; k0 += BKK) {
    __syncthreads();
#pragma unroll
    for (int i = 0; i < 4; ++i) {
      int f  = i * 256 + tid;
      int r  = f >> 3;
      int kk = (f & 7) << 3;
      size_t ga = (size_t)(by * BM + r) * K + k0 + kk;
      size_t gb = (size_t)(bx * BN + r) * K + k0 + kk;
      *reinterpret_cast<bf16x8*>(&sAh[r][kk]) = *reinterpret_cast<const bf16x8*>(Ah + ga);
      *reinterpret_cast<bf16x8*>(&sAl[r][kk]) = *reinterpret_cast<const bf16x8*>(Al + ga);
      *reinterpret_cast<bf16x8*>(&sBh[r][kk]) = *reinterpret_cast<const bf16x8*>(Bh + gb);
      *reinterpret_cast<bf16x8*>(&sBl[r][kk]) = *reinterpret_cast<const bf16x8*>(Bl + gb);
    }
    __syncthreads();
#pragma unroll
    for (int kk = 0; kk < BKK; kk += 32) {
      const int kf = kk + (l4 << 3);
      bf16x8 a_h[4], a_l[4], b_h[4], b_l[4];
#pragma unroll
      for (int m = 0; m < 4; ++m) {
        a_h[m] = *reinterpret_cast<const bf16x8*>(&sAh[wr * 64 + m * 16 + l15][kf]);
        a_l[m] = *reinterpret_cast<const bf16x8*>(&sAl[wr * 64 + m * 16 + l15][kf]);
      }
#pragma unroll
      for (int n = 0; n < 4; ++n) {
        b_h[n] = *reinterpret_cast<const bf16x8*>(&sBh[wc * 64 + n * 16 + l15][kf]);
        b_l[n] = *reinterpret_cast<const bf16x8*>(&sBl[wc * 64 + n * 16 + l15][kf]);
      }
#pragma unroll
      for (int m = 0; m < 4; ++m)
#pragma unroll
        for (int n = 0; n < 4; ++n) {
          acc[m][n] = __builtin_amdgcn_mfma_f32_16x16x32_bf16(a_h[m], b_h[n], acc[m][n], 0, 0, 0);
          acc[m][n] = __builtin_amdgcn_mfma_f32_16x16x32_bf16(a_l[m], b_h[n], acc[m][n], 0, 0, 0);
          acc[m][n] = __builtin_amdgcn_mfma_f32_16x16x32_bf16(a_h[m], b_l[n], acc[m][n], 0, 0, 0);
        }
    }
  }
#pragma unroll
  for (int n = 0; n < 4; ++n) {
    int col = bx * BN + wc * 64 + n * 16 + l15;
    float bv = bias1[col] + bias2[col];
#pragma unroll
    for (int m = 0; m < 4; ++m) {
#pragma unroll
      for (int r = 0; r < 4; ++r) {
        int row = by * BM + wr * 64 + m * 16 + l4 * 4 + r;
        C[(size_t)row * N + col] = acc[m][n][r] + bv;
      }
    }
  }
}

// ---------------- one LSTM timestep (fp32 exact) ----------------
// grid = HH/4 WGs; WG owns 4 h-columns (16 gate rows). h ping-pong.
__global__ __launch_bounds__(256) void lstm_step(
    const float* __restrict__ xg,     // [BB][NG4] this timestep (bias included)
    const float* __restrict__ whh,    // [NG4][HH]
    const float* __restrict__ hprev,  // [BB][HH]
    float* __restrict__ hnext,        // [BB][HH]
    float* __restrict__ cst,          // [BB][HH] in-place
    bf16* __restrict__ out_hi,        // [BB][HH] or null
    bf16* __restrict__ out_lo,        // [BB][HH] or null
    float* __restrict__ out_f32)      // [BB][HH] or null
{
  __shared__ float h_lds[BB][129];
  __shared__ float w_lds[16][128];
  __shared__ float g_lds[4][4][BB];

  const int tid  = threadIdx.x;
  const int b    = tid & 63;
  const int gate = tid >> 6;
  const int j0   = blockIdx.x << 2;

  const int wr_ = tid >> 4;           // 0..15 : staging row = gate*4 + c
  const int wk_ = (tid & 15) << 3;    // 0..120
  const size_t wrow = (size_t)((wr_ >> 2) * HH + j0 + (wr_ & 3)) * HH + wk_;

  float acc0 = 0.f, acc1 = 0.f, acc2 = 0.f, acc3 = 0.f;

  for (int k0 = 0; k0 < HH; k0 += 128) {
    __syncthreads();
    // stage h chunk [64][128]
#pragma unroll
    for (int i = 0; i < 8; ++i) {
      int f = i * 1024 + tid * 4;
      int r = f >> 7, kk = f & 127;
      float4 v = *reinterpret_cast<const float4*>(hprev + (size_t)r * HH + k0 + kk);
      h_lds[r][kk]     = v.x;
      h_lds[r][kk + 1] = v.y;
      h_lds[r][kk + 2] = v.z;
      h_lds[r][kk + 3] = v.w;
    }
    // stage w slice [16][128]
    {
      float4 v0 = *reinterpret_cast<const float4*>(whh + wrow + k0);
      float4 v1 = *reinterpret_cast<const float4*>(whh + wrow + k0 + 4);
      *reinterpret_cast<float4*>(&w_lds[wr_][wk_])     = v0;
      *reinterpret_cast<float4*>(&w_lds[wr_][wk_ + 4]) = v1;
    }
    __syncthreads();
    const float* w0p = &w_lds[gate * 4 + 0][0];
    const float* w1p = &w_lds[gate * 4 + 1][0];
    const float* w2p = &w_lds[gate * 4 + 2][0];
    const float* w3p = &w_lds[gate * 4 + 3][0];
    const float* hp  = &h_lds[b][0];
#pragma unroll
    for (int k = 0; k < 128; k += 4) {
      float4 wv0 = *reinterpret_cast<const float4*>(w0p + k);
      float4 wv1 = *reinterpret_cast<const float4*>(w1p + k);
      float4 wv2 = *reinterpret_cast<const float4*>(w2p + k);
      float4 wv3 = *reinterpret_cast<const float4*>(w3p + k);
      float h0v = hp[k], h1v = hp[k + 1], h2v = hp[k + 2], h3v = hp[k + 3];
      acc0 = fmaf(h0v, wv0.x, acc0); acc0 = fmaf(h1v, wv0.y, acc0);
      acc0 = fmaf(h2v, wv0.z, acc0); acc0 = fmaf(h3v, wv0.w, acc0);
      acc1 = fmaf(h0v, wv1.x, acc1); acc1 = fmaf(h1v, wv1.y, acc1);
      acc1 = fmaf(h2v, wv1.z, acc1); acc1 = fmaf(h3v, wv1.w, acc1);
      acc2 = fmaf(h0v, wv2.x, acc2); acc2 = fmaf(h1v, wv2.y, acc2);
      acc2 = fmaf(h2v, wv2.z, acc2); acc2 = fmaf(h3v, wv2.w, acc2);
      acc3 = fmaf(h0v, wv3.x, acc3); acc3 = fmaf(h1v, wv3.y, acc3);
      acc3 = fmaf(h2v, wv3.z, acc3); acc3 = fmaf(h3v, wv3.w, acc3);
    }
  }

  // add xg, exchange gates through LDS
  {
    const size_t xb = (size_t)b * NG4 + gate * HH + j0;
    float4 xv = *reinterpret_cast<const float4*>(xg + xb);
    g_lds[gate][0][b] = acc0 + xv.x;
    g_lds[gate][1][b] = acc1 + xv.y;
    g_lds[gate][2][b] = acc2 + xv.z;
    g_lds[gate][3][b] = acc3 + xv.w;
  }
  __syncthreads();
  {
    const int cc = tid >> 6;
    const int b2 = tid & 63;
    float iv = g_lds[0][cc][b2];
    float fv = g_lds[1][cc][b2];
    float gv = g_lds[2][cc][b2];
    float ov = g_lds[3][cc][b2];
    iv = 1.f / (1.f + __expf(-iv));
    fv = 1.f / (1.f + __expf(-fv));
    gv = tanhf(gv);
    ov = 1.f / (1.f + __expf(-ov));
    const size_t idx = (size_t)b2 * HH + j0 + cc;
    float cv = fv * cst[idx] + iv * gv;
    float hv = ov * tanhf(cv);
    cst[idx]   = cv;
    hnext[idx] = hv;
    if (out_hi) {
      bf16 hb = __float2bfloat16(hv);
      out_hi[idx] = hb;
      out_lo[idx] = __float2bfloat16(hv - __bfloat162float(hb));
    }
    if (out_f32) out_f32[idx] = hv;
  }
}

extern "C" void kernel_launch(void* const* d_in, const int* in_sizes, int n_in,
                              void* d_out, int out_size, void* d_ws, size_t ws_size,
                              hipStream_t stream) {
  const float* x    = (const float*)d_in[0];
  const float* wih0 = (const float*)d_in[1];
  const float* whh0 = (const float*)d_in[2];
  const float* bih0 = (const float*)d_in[3];
  const float* bhh0 = (const float*)d_in[4];
  const float* wih1 = (const float*)d_in[5];
  const float* whh1 = (const float*)d_in[6];
  const float* bih1 = (const float*)d_in[7];
  const float* bhh1 = (const float*)d_in[8];
  float* out = (float*)d_out;

  // pick chunk size (timesteps per xg buffer) by available workspace
  int ct = 64;
  for (;;) {
    size_t fixed = (size_t)TT * BB * DD * 2 * 2     // x hi/lo
                 + (size_t)NG4 * DD * 2 * 2         // wih0 hi/lo
                 + (size_t)NG4 * HH * 2 * 2         // wih1 hi/lo
                 + (size_t)6 * BB * HH * 4          // states
                 + ((size_t)1 << 16);               // align slack
    size_t var = (size_t)2 * ct * BB * NG4 * 4 + (size_t)2 * ct * BB * HH * 2;
    if (fixed + var <= ws_size || ct == 8) break;
    ct >>= 1;
  }
  const int nch = TT / ct;

  char* ws = (char*)d_ws;
  size_t off = 0;
  auto alloc = [&](size_t bytes) -> char* {
    char* p = ws + off;
    off += (bytes + 255) & ~(size_t)255;
    return p;
  };
  bf16*  xh  = (bf16*)alloc((size_t)TT * BB * DD * 2);
  bf16*  xl  = (bf16*)alloc((size_t)TT * BB * DD * 2);
  bf16*  w0h = (bf16*)alloc((size_t)NG4 * DD * 2);
  bf16*  w0l = (bf16*)alloc((size_t)NG4 * DD * 2);
  bf16*  w1h = (bf16*)alloc((size_t)NG4 * HH * 2);
  bf16*  w1l = (bf16*)alloc((size_t)NG4 * HH * 2);
  bf16*  h1h = (bf16*)alloc((size_t)ct * BB * HH * 2);
  bf16*  h1l = (bf16*)alloc((size_t)ct * BB * HH * 2);
  float* xg0 = (float*)alloc((size_t)ct * BB * NG4 * 4);
  float* xg1 = (float*)alloc((size_t)ct * BB * NG4 * 4);
  float* h0a = (float*)alloc((size_t)BB * HH * 4);
  float* h0b = (float*)alloc((size_t)BB * HH * 4);
  float* c0  = (float*)alloc((size_t)BB * HH * 4);
  float* h1a = (float*)alloc((size_t)BB * HH * 4);
  float* h1b = (float*)alloc((size_t)BB * HH * 4);
  float* c1  = (float*)alloc((size_t)BB * HH * 4);

  cast_hilo<<<(TT * BB * DD / 4 + 255) / 256, 256, 0, stream>>>(x, xh, xl, TT * BB * DD / 4);
  cast_hilo<<<(NG4 * DD / 4 + 255) / 256, 256, 0, stream>>>(wih0, w0h, w0l, NG4 * DD / 4);
  cast_hilo<<<(NG4 * HH / 4 + 255) / 256, 256, 0, stream>>>(wih1, w1h, w1l, NG4 * HH / 4);

  hipMemsetAsync(h0a, 0, (size_t)BB * HH * 4, stream);
  hipMemsetAsync(c0,  0, (size_t)BB * HH * 4, stream);
  hipMemsetAsync(h1a, 0, (size_t)BB * HH * 4, stream);
  hipMemsetAsync(c1,  0, (size_t)BB * HH * 4, stream);

  const int gemmGrid = (ct * BB / BM) * (NG4 / BN);

  for (int ch = 0; ch < nch; ++ch) {
    gemm3<<<gemmGrid, 256, 0, stream>>>(xh + (size_t)ch * ct * BB * DD,
                                        xl + (size_t)ch * ct * BB * DD,
                                        w0h, w0l, bih0, bhh0, xg0, ct * BB, NG4, DD);
    for (int tl = 0; tl < ct; ++tl) {
      int t = ch * ct + tl;
      float* hr = (t & 1) ? h0b : h0a;
      float* hw = (t & 1) ? h0a : h0b;
      lstm_step<<<HH / 4, 256, 0, stream>>>(xg0 + (size_t)tl * BB * NG4, whh0, hr, hw, c0,
                                            h1h + (size_t)tl * BB * HH,
                                            h1l + (size_t)tl * BB * HH,
                                            (float*)nullptr);
    }
    gemm3<<<gemmGrid, 256, 0, stream>>>(h1h, h1l, w1h, w1l, bih1, bhh1, xg1, ct * BB, NG4, HH);
    for (int tl = 0; tl < ct; ++tl) {
      int t = ch * ct + tl;
      float* hr = (t & 1) ? h1b : h1a;
      float* hw = (t & 1) ? h1a : h1b;
      lstm_step<<<HH / 4, 256, 0, stream>>>(xg1 + (size_t)tl * BB * NG4, whh1, hr, hw, c1,
                                            (bf16*)nullptr, (bf16*)nullptr,
                                            out + (size_t)t * BB * HH);
    }
  }
}

// Round 2
// 17921.817 us; speedup vs baseline: 3.8070x; 3.8070x over previous
//
#include <hip/hip_runtime.h>
#include <hip/hip_bf16.h>

#define TT 512
#define BB 64
#define DD 1024
#define HH 1024
#define NG4 4096

typedef short bf16x8 __attribute__((ext_vector_type(8)));
typedef float f32x4 __attribute__((ext_vector_type(4)));
typedef __hip_bfloat16 bf16;

// ---------------- cast: fp32 -> bf16 hi + bf16 lo(residual) ----------------
__global__ __launch_bounds__(256) void cast_hilo(const float* __restrict__ in,
                                                 bf16* __restrict__ hi,
                                                 bf16* __restrict__ lo,
                                                 int n4) {
  int i = blockIdx.x * 256 + threadIdx.x;
  if (i >= n4) return;
  float4 v = reinterpret_cast<const float4*>(in)[i];
  float f[4] = {v.x, v.y, v.z, v.w};
  int base = i * 4;
#pragma unroll
  for (int j = 0; j < 4; ++j) {
    bf16 h = __float2bfloat16(f[j]);
    hi[base + j] = h;
    lo[base + j] = __float2bfloat16(f[j] - __bfloat162float(h));
  }
}

// ---------------- pack w_hh rows for the step kernel ----------------
// packed row p = g*32 + q*8 + u  <->  original row q*1024 + g*8 + u
// (WG g of the step kernel owns hidden units j = g*8+u, gate q)
__global__ __launch_bounds__(256) void pack_whh(const float* __restrict__ w,
                                                bf16* __restrict__ wh,
                                                bf16* __restrict__ wl) {
  int idx = blockIdx.x * 256 + threadIdx.x;   // one thread = 8 elements
  int p   = idx >> 7;
  int kk  = (idx & 127) << 3;
  int g = p >> 5, c = p & 31, q = c >> 3, u = c & 7;
  size_t src = ((size_t)(q << 10) + (g << 3) + u) * HH + kk;
  size_t dst = (size_t)p * HH + kk;
  float4 v0 = *reinterpret_cast<const float4*>(w + src);
  float4 v1 = *reinterpret_cast<const float4*>(w + src + 4);
  float f[8] = {v0.x, v0.y, v0.z, v0.w, v1.x, v1.y, v1.z, v1.w};
  short ho[8], lo[8];
#pragma unroll
  for (int j = 0; j < 8; ++j) {
    bf16 h = __float2bfloat16(f[j]);
    ho[j] = *reinterpret_cast<short*>(&h);
    bf16 l = __float2bfloat16(f[j] - __bfloat162float(h));
    lo[j] = *reinterpret_cast<short*>(&l);
  }
  *reinterpret_cast<bf16x8*>(wh + dst) = *reinterpret_cast<bf16x8*>(ho);
  *reinterpret_cast<bf16x8*>(wl + dst) = *reinterpret_cast<bf16x8*>(lo);
}

// ---------------- 3-term split-bf16 MFMA GEMM: C = A*B^T + bias1 + bias2 ----
#define BM 128
#define BN 128
#define BKK 64

__global__ __launch_bounds__(256) void gemm3(
    const bf16* __restrict__ Ah, const bf16* __restrict__ Al,
    const bf16* __restrict__ Bh, const bf16* __restrict__ Bl,
    const float* __restrict__ bias1, const float* __restrict__ bias2,
    float* __restrict__ C, int M, int N, int K)
{
  __shared__ bf16 sAh[BM][BKK], sAl[BM][BKK], sBh[BN][BKK], sBl[BN][BKK];
  const int tid  = threadIdx.x;
  const int lane = tid & 63;
  const int wv   = tid >> 6;
  const int wr   = wv >> 1, wc = wv & 1;
  const int nbx  = N / BN;
  const int bx   = blockIdx.x % nbx, by = blockIdx.x / nbx;
  const int l15  = lane & 15, l4 = lane >> 4;

  f32x4 acc[4][4] = {};

  for (int k0 = 0; k0 < K; k0 += BKK) {
    __syncthreads();
#pragma unroll
    for (int i = 0; i < 4; ++i) {
      int f  = i * 256 + tid;
      int r  = f >> 3;
      int kk = (f & 7) << 3;
      size_t ga = (size_t)(by * BM + r) * K + k0 + kk;
      size_t gb = (size_t)(bx * BN + r) * K + k0 + kk;
      *reinterpret_cast<bf16x8*>(&sAh[r][kk]) = *reinterpret_cast<const bf16x8*>(Ah + ga);
      *reinterpret_cast<bf16x8*>(&sAl[r][kk]) = *reinterpret_cast<const bf16x8*>(Al + ga);
      *reinterpret_cast<bf16x8*>(&sBh[r][kk]) = *reinterpret_cast<const bf16x8*>(Bh + gb);
      *reinterpret_cast<bf16x8*>(&sBl[r][kk]) = *reinterpret_cast<const bf16x8*>(Bl + gb);
    }
    __syncthreads();
#pragma unroll
    for (int kk = 0; kk < BKK; kk += 32) {
      const int kf = kk + (l4 << 3);
      bf16x8 a_h[4], a_l[4], b_h[4], b_l[4];
#pragma unroll
      for (int m = 0; m < 4; ++m) {
        a_h[m] = *reinterpret_cast<const bf16x8*>(&sAh[wr * 64 + m * 16 + l15][kf]);
        a_l[m] = *reinterpret_cast<const bf16x8*>(&sAl[wr * 64 + m * 16 + l15][kf]);
      }
#pragma unroll
      for (int n = 0; n < 4; ++n) {
        b_h[n] = *reinterpret_cast<const bf16x8*>(&sBh[wc * 64 + n * 16 + l15][kf]);
        b_l[n] = *reinterpret_cast<const bf16x8*>(&sBl[wc * 64 + n * 16 + l15][kf]);
      }
#pragma unroll
      for (int m = 0; m < 4; ++m)
#pragma unroll
        for (int n = 0; n < 4; ++n) {
          acc[m][n] = __builtin_amdgcn_mfma_f32_16x16x32_bf16(a_h[m], b_h[n], acc[m][n], 0, 0, 0);
          acc[m][n] = __builtin_amdgcn_mfma_f32_16x16x32_bf16(a_l[m], b_h[n], acc[m][n], 0, 0, 0);
          acc[m][n] = __builtin_amdgcn_mfma_f32_16x16x32_bf16(a_h[m], b_l[n], acc[m][n], 0, 0, 0);
        }
    }
  }
#pragma unroll
  for (int n = 0; n < 4; ++n) {
    int col = bx * BN + wc * 64 + n * 16 + l15;
    float bv = bias1[col] + bias2[col];
#pragma unroll
    for (int m = 0; m < 4; ++m) {
#pragma unroll
      for (int r = 0; r < 4; ++r) {
        int row = by * BM + wr * 64 + m * 16 + l4 * 4 + r;
        C[(size_t)row * N + col] = acc[m][n][r] + bv;
      }
    }
  }
}

// ---------------- one LSTM timestep via 3-term MFMA ----------------
// 128 WGs x 256 threads; WG g owns hidden units j0=g*8..+8 (32 packed gate rows).
// gates[64][32] = h[64][1024] @ wpk[g]^T  (bf16 hi/lo 3-term), then fp32 pointwise.
__global__ __launch_bounds__(256) void lstm_step_mfma(
    const bf16* __restrict__ wh, const bf16* __restrict__ wl,  // packed [4096][1024]
    const bf16* __restrict__ hph, const bf16* __restrict__ hpl,// hprev hi/lo [64][1024]
    const float* __restrict__ xg,                              // [64][4096] (biases included)
    float* __restrict__ cst,                                   // [64][1024] in-place
    bf16* __restrict__ hnh, bf16* __restrict__ hnl,            // hnext hi/lo
    bf16* __restrict__ svh, bf16* __restrict__ svl,            // optional dup-save (layer0)
    float* __restrict__ out_f32)                               // optional fp32 out (layer1)
{
  __shared__ bf16 sAh[64][128], sAl[64][128], sBh[32][128], sBl[32][128];
  __shared__ float gbuf[4][16][33];

  const int tid  = threadIdx.x;
  const int lane = tid & 63;
  const int wv   = tid >> 6;
  const int l15  = lane & 15, l4 = lane >> 4;
  const int g    = blockIdx.x;
  const int j0   = g << 3;

  f32x4 acc[2] = {};

  for (int k0 = 0; k0 < HH; k0 += 128) {
    __syncthreads();
    // stage h chunk [64][128] hi/lo (XOR-swizzled cols, 16B granularity)
#pragma unroll
    for (int i = 0; i < 4; ++i) {
      int f  = i * 256 + tid;
      int r  = f >> 4;
      int kk = (f & 15) << 3;
      int ks = kk ^ ((r & 7) << 3);
      size_t src = (size_t)r * HH + k0 + kk;
      *reinterpret_cast<bf16x8*>(&sAh[r][ks]) = *reinterpret_cast<const bf16x8*>(hph + src);
      *reinterpret_cast<bf16x8*>(&sAl[r][ks]) = *reinterpret_cast<const bf16x8*>(hpl + src);
    }
    // stage w slice [32][128] hi/lo
#pragma unroll
    for (int i = 0; i < 2; ++i) {
      int f  = i * 256 + tid;
      int r  = f >> 4;
      int kk = (f & 15) << 3;
      int ks = kk ^ ((r & 7) << 3);
      size_t src = (size_t)(g * 32 + r) * HH + k0 + kk;
      *reinterpret_cast<bf16x8*>(&sBh[r][ks]) = *reinterpret_cast<const bf16x8*>(wh + src);
      *reinterpret_cast<bf16x8*>(&sBl[r][ks]) = *reinterpret_cast<const bf16x8*>(wl + src);
    }
    __syncthreads();
#pragma unroll
    for (int ks = 0; ks < 4; ++ks) {
      const int kf   = ks * 32 + (l4 << 3);
      const int arow = wv * 16 + l15;
      const int asw  = kf ^ ((arow & 7) << 3);
      bf16x8 ah = *reinterpret_cast<const bf16x8*>(&sAh[arow][asw]);
      bf16x8 al = *reinterpret_cast<const bf16x8*>(&sAl[arow][asw]);
#pragma unroll
      for (int n = 0; n < 2; ++n) {
        const int brow = n * 16 + l15;
        const int bsw  = kf ^ ((brow & 7) << 3);
        bf16x8 bh = *reinterpret_cast<const bf16x8*>(&sBh[brow][bsw]);
        bf16x8 bl = *reinterpret_cast<const bf16x8*>(&sBl[brow][bsw]);
        acc[n] = __builtin_amdgcn_mfma_f32_16x16x32_bf16(ah, bh, acc[n], 0, 0, 0);
        acc[n] = __builtin_amdgcn_mfma_f32_16x16x32_bf16(al, bh, acc[n], 0, 0, 0);
        acc[n] = __builtin_amdgcn_mfma_f32_16x16x32_bf16(ah, bl, acc[n], 0, 0, 0);
      }
    }
  }

  // wave-private gate exchange: gbuf[wv][batch_local][packed_col]
#pragma unroll
  for (int n = 0; n < 2; ++n)
#pragma unroll
    for (int r = 0; r < 4; ++r)
      gbuf[wv][l4 * 4 + r][n * 16 + l15] = acc[n][r];

  // pointwise update: 2 items per lane (16 batches x 8 units per wave)
#pragma unroll
  for (int s = 0; s < 2; ++s) {
    int item = s * 64 + lane;
    int u  = item & 7;
    int bl = item >> 3;
    int batch = wv * 16 + bl;
    int j = j0 + u;
    float iv = gbuf[wv][bl][u];
    float fv = gbuf[wv][bl][8 + u];
    float gv = gbuf[wv][bl][16 + u];
    float ov = gbuf[wv][bl][24 + u];
    const float* xp = xg + (size_t)batch * NG4 + j;
    iv += xp[0];
    fv += xp[1024];
    gv += xp[2048];
    ov += xp[3072];
    iv = 1.f / (1.f + __expf(-iv));
    fv = 1.f / (1.f + __expf(-fv));
    gv = tanhf(gv);
    ov = 1.f / (1.f + __expf(-ov));
    const size_t idx = (size_t)batch * HH + j;
    float cv = fv * cst[idx] + iv * gv;
    float hv = ov * tanhf(cv);
    cst[idx] = cv;
    bf16 hb = __float2bfloat16(hv);
    bf16 lb = __float2bfloat16(hv - __bfloat162float(hb));
    hnh[idx] = hb;
    hnl[idx] = lb;
    if (svh) { svh[idx] = hb; svl[idx] = lb; }
    if (out_f32) out_f32[idx] = hv;
  }
}

extern "C" void kernel_launch(void* const* d_in, const int* in_sizes, int n_in,
                              void* d_out, int out_size, void* d_ws, size_t ws_size,
                              hipStream_t stream) {
  const float* x    = (const float*)d_in[0];
  const float* wih0 = (const float*)d_in[1];
  const float* whh0 = (const float*)d_in[2];
  const float* bih0 = (const float*)d_in[3];
  const float* bhh0 = (const float*)d_in[4];
  const float* wih1 = (const float*)d_in[5];
  const float* whh1 = (const float*)d_in[6];
  const float* bih1 = (const float*)d_in[7];
  const float* bhh1 = (const float*)d_in[8];
  float* out = (float*)d_out;

  // pick chunk size (timesteps per xg buffer) by available workspace
  int ct = 64;
  for (;;) {
    size_t fixed = (size_t)TT * BB * DD * 2 * 2        // x hi/lo
                 + (size_t)NG4 * DD * 2 * 2            // wih0 hi/lo
                 + (size_t)NG4 * HH * 2 * 2            // wih1 hi/lo
                 + (size_t)NG4 * HH * 2 * 2 * 2        // packed whh0/1 hi/lo
                 + (size_t)8 * BB * HH * 2             // h ping-pong hi/lo x2 layers
                 + (size_t)2 * BB * HH * 4              // c states
                 + ((size_t)1 << 18);                   // align slack
    size_t var = (size_t)2 * ct * BB * NG4 * 4 + (size_t)2 * ct * BB * HH * 2;
    if (fixed + var <= ws_size || ct == 8) break;
    ct >>= 1;
  }
  const int nch = TT / ct;

  char* ws = (char*)d_ws;
  size_t off = 0;
  auto alloc = [&](size_t bytes) -> char* {
    char* p = ws + off;
    off += (bytes + 255) & ~(size_t)255;
    return p;
  };
  bf16*  xh   = (bf16*)alloc((size_t)TT * BB * DD * 2);
  bf16*  xl   = (bf16*)alloc((size_t)TT * BB * DD * 2);
  bf16*  w0h  = (bf16*)alloc((size_t)NG4 * DD * 2);
  bf16*  w0l  = (bf16*)alloc((size_t)NG4 * DD * 2);
  bf16*  w1h  = (bf16*)alloc((size_t)NG4 * HH * 2);
  bf16*  w1l  = (bf16*)alloc((size_t)NG4 * HH * 2);
  bf16*  wr0h = (bf16*)alloc((size_t)NG4 * HH * 2);   // packed recurrent weights
  bf16*  wr0l = (bf16*)alloc((size_t)NG4 * HH * 2);
  bf16*  wr1h = (bf16*)alloc((size_t)NG4 * HH * 2);
  bf16*  wr1l = (bf16*)alloc((size_t)NG4 * HH * 2);
  bf16*  h1h  = (bf16*)alloc((size_t)ct * BB * HH * 2);
  bf16*  h1l  = (bf16*)alloc((size_t)ct * BB * HH * 2);
  float* xg0  = (float*)alloc((size_t)ct * BB * NG4 * 4);
  float* xg1  = (float*)alloc((size_t)ct * BB * NG4 * 4);
  bf16*  h0Ah = (bf16*)alloc((size_t)BB * HH * 2);
  bf16*  h0Al = (bf16*)alloc((size_t)BB * HH * 2);
  bf16*  h0Bh = (bf16*)alloc((size_t)BB * HH * 2);
  bf16*  h0Bl = (bf16*)alloc((size_t)BB * HH * 2);
  bf16*  h1Ah = (bf16*)alloc((size_t)BB * HH * 2);
  bf16*  h1Al = (bf16*)alloc((size_t)BB * HH * 2);
  bf16*  h1Bh = (bf16*)alloc((size_t)BB * HH * 2);
  bf16*  h1Bl = (bf16*)alloc((size_t)BB * HH * 2);
  float* c0   = (float*)alloc((size_t)BB * HH * 4);
  float* c1   = (float*)alloc((size_t)BB * HH * 4);

  cast_hilo<<<(TT * BB * DD / 4 + 255) / 256, 256, 0, stream>>>(x, xh, xl, TT * BB * DD / 4);
  cast_hilo<<<(NG4 * DD / 4 + 255) / 256, 256, 0, stream>>>(wih0, w0h, w0l, NG4 * DD / 4);
  cast_hilo<<<(NG4 * HH / 4 + 255) / 256, 256, 0, stream>>>(wih1, w1h, w1l, NG4 * HH / 4);
  pack_whh<<<NG4 * HH / 8 / 256, 256, 0, stream>>>(whh0, wr0h, wr0l);
  pack_whh<<<NG4 * HH / 8 / 256, 256, 0, stream>>>(whh1, wr1h, wr1l);

  hipMemsetAsync(h0Ah, 0, (size_t)BB * HH * 2, stream);
  hipMemsetAsync(h0Al, 0, (size_t)BB * HH * 2, stream);
  hipMemsetAsync(h1Ah, 0, (size_t)BB * HH * 2, stream);
  hipMemsetAsync(h1Al, 0, (size_t)BB * HH * 2, stream);
  hipMemsetAsync(c0, 0, (size_t)BB * HH * 4, stream);
  hipMemsetAsync(c1, 0, (size_t)BB * HH * 4, stream);

  const int gemmGrid = (ct * BB / BM) * (NG4 / BN);

  for (int ch = 0; ch < nch; ++ch) {
    gemm3<<<gemmGrid, 256, 0, stream>>>(xh + (size_t)ch * ct * BB * DD,
                                        xl + (size_t)ch * ct * BB * DD,
                                        w0h, w0l, bih0, bhh0, xg0, ct * BB, NG4, DD);
    for (int tl = 0; tl < ct; ++tl) {
      int t = ch * ct + tl;
      bf16* rh = (t & 1) ? h0Bh : h0Ah;
      bf16* rl = (t & 1) ? h0Bl : h0Al;
      bf16* wh_ = (t & 1) ? h0Ah : h0Bh;
      bf16* wl_ = (t & 1) ? h0Al : h0Bl;
      lstm_step_mfma<<<128, 256, 0, stream>>>(wr0h, wr0l, rh, rl,
                                              xg0 + (size_t)tl * BB * NG4, c0,
                                              wh_, wl_,
                                              h1h + (size_t)tl * BB * HH,
                                              h1l + (size_t)tl * BB * HH,
                                              (float*)nullptr);
    }
    gemm3<<<gemmGrid, 256, 0, stream>>>(h1h, h1l, w1h, w1l, bih1, bhh1, xg1, ct * BB, NG4, HH);
    for (int tl = 0; tl < ct; ++tl) {
      int t = ch * ct + tl;
      bf16* rh = (t & 1) ? h1Bh : h1Ah;
      bf16* rl = (t & 1) ? h1Bl : h1Al;
      bf16* wh_ = (t & 1) ? h1Ah : h1Bh;
      bf16* wl_ = (t & 1) ? h1Al : h1Bl;
      lstm_step_mfma<<<128, 256, 0, stream>>>(wr1h, wr1l, rh, rl,
                                              xg1 + (size_t)tl * BB * NG4, c1,
                                              wh_, wl_,
                                              (bf16*)nullptr, (bf16*)nullptr,
                                              out + (size_t)t * BB * HH);
    }
  }
}